// Round 1
// baseline (473.858 us; speedup 1.0000x reference)
//
#include <hip/hip_runtime.h>
#include <math.h>

// Problem constants (from reference):
//   B=64, A=64, MULS=((64,0),(32,1),(16,2)) -> DIM_IN=240, NB=32, H=128, MOUT=112
//   MAX_R=10, BETA=5, EPS=1e-12
#define NB_ 32
#define H_ 128
#define MOUT_ 112

#define INV_STEP 3.1f                 // (NB-1)/MAX_R = 31/10
#define HALF_PI 1.57079632679489662f
#define INV_SQRT_NB 0.17677669529663689f   // 1/sqrt(32)
#define INV_SQRT_H 0.08838834764831845f    // 1/sqrt(128)
#define NORM0 0.125f                  // 1/sqrt(1*64)
#define NORM1 0.10206207261596575f    // 1/sqrt(3*32)
#define NORM2 0.11180339887498948f    // 1/sqrt(5*16)
#define S3 1.7320508075688772f
#define S5 2.23606797749979f
#define S15 3.872983346207417f
#define LN2 0.6931471805599453f

__device__ __forceinline__ float ssp_f(float x) {
    // (softplus(5x) - ln2) / 5, numerically stable
    float t = 5.0f * x;
    float s = fmaxf(t, 0.0f) + log1pf(__expf(-fabsf(t)));
    return (s - LN2) * 0.2f;
}
__device__ __forceinline__ float sp_f(float x) {
    float t = 5.0f * x;
    float s = fmaxf(t, 0.0f) + log1pf(__expf(-fabsf(t)));
    return s * 0.2f;
}

// One block per (z, a). 256 threads. All 64 b-pairs handled as small in-LDS GEMMs.
__global__ __launch_bounds__(256, 2)
void outnet_kernel(const float* __restrict__ rep,    // (64,64,240)
                   const float* __restrict__ geom,   // (64,64,3)
                   const float* __restrict__ mask,   // (64,64)
                   const float* __restrict__ W1,     // (32,128)
                   const float* __restrict__ W2,     // (128,128)
                   const float* __restrict__ W3,     // (128,112)
                   float* __restrict__ out)          // (64,64,1)
{
    const int a = blockIdx.x;
    const int z = blockIdx.y;
    const int tid = threadIdx.x;

    // sBig: [0:8192) = H1[64][128]; [8192:16384) = H2[64][128];
    // after layer3, Rw[64][112] aliases [0:7168) (H1 region, dead by then).
    __shared__ __align__(16) float sBig[2 * 64 * 128];   // 64 KB
    __shared__ float sGeom[64][3];
    __shared__ float sMask[64];
    __shared__ float sR[64];
    __shared__ float sY1[64][3];
    __shared__ float sY2[64][5];
    __shared__ float sPart[256];
    __shared__ float sInv;

    float* sH1 = sBig;
    float* sH2 = sBig + 64 * H_;
    float* sRw = sBig;   // alias, used after layer3

    // ---------------- Phase 0: geometry / mask / SH setup ----------------
    if (tid < 64) {
        sGeom[tid][0] = geom[(z * 64 + tid) * 3 + 0];
        sGeom[tid][1] = geom[(z * 64 + tid) * 3 + 1];
        sGeom[tid][2] = geom[(z * 64 + tid) * 3 + 2];
        sMask[tid] = mask[z * 64 + tid];
    }
    __syncthreads();
    if (tid == 0) {
        float s = 0.f;
        for (int i = 0; i < 64; ++i) s += sMask[i];
        sInv = rsqrtf(s);   // feats scale 1/sqrt(n_atoms), folded in at the end
    }
    if (tid < 64) {
        const int b = tid;
        float dx = sGeom[a][0] - sGeom[b][0];
        float dy = sGeom[a][1] - sGeom[b][1];
        float dz = sGeom[a][2] - sGeom[b][2];
        float r2 = dx * dx + dy * dy + dz * dz;
        float r = sqrtf(fmaxf(r2, 1e-12f));
        float nz = (r2 > 1e-10f) ? 1.0f : 0.0f;
        float inv_r = 1.0f / r;
        float x = dx * inv_r, y = dy * inv_r, zz = dz * inv_r;
        sR[b] = r;
        sY1[b][0] = S3 * x * nz;
        sY1[b][1] = S3 * y * nz;
        sY1[b][2] = S3 * zz * nz;
        sY2[b][0] = S15 * x * y * nz;
        sY2[b][1] = S15 * y * zz * nz;
        sY2[b][2] = 0.5f * S5 * (3.0f * zz * zz - 1.0f) * nz;
        sY2[b][3] = S15 * x * zz * nz;
        sY2[b][4] = 0.5f * S15 * (x * x - y * y) * nz;
    }
    __syncthreads();

    // ---------------- Phase 1: layer 1 (sparse cosine basis: <=2 nonzeros) ----
    // h1[b][col] = ssp( (sum_i basis[b][i]*W1[i][col]) / sqrt(NB) )
    {
        const int col = tid & 127;
        const int rbase = (tid >> 7) * 32;
        for (int rr = 0; rr < 32; ++rr) {
            const int b = rbase + rr;
            float u = sR[b] * INV_STEP;       // r/step
            int i0 = (int)floorf(u);
            float acc = 0.f;
            float d0 = u - (float)i0;         // in [0,1)
            if (i0 >= 0 && i0 < NB_ && d0 < 1.0f)
                acc += __cosf(HALF_PI * d0) * W1[i0 * H_ + col];
            int i1 = i0 + 1;
            float d1 = d0 - 1.0f;             // in [-1,0)
            if (i1 >= 0 && i1 < NB_ && d1 > -1.0f)
                acc += __cosf(HALF_PI * d1) * W1[i1 * H_ + col];
            sH1[b * H_ + col] = ssp_f(acc * INV_SQRT_NB);
        }
    }
    __syncthreads();

    // ---------------- Phase 2: layer 2  H2[64][128] = ssp(H1 @ W2 / sqrt(H)) ---
    // 256 threads = 16 rowTiles(4 rows) x 16 colTiles(8 cols)
    {
        const int rt = tid >> 4, ct = tid & 15;
        const int r0 = rt * 4, c0 = ct * 8;
        float acc[4][8];
        #pragma unroll
        for (int r = 0; r < 4; ++r)
            #pragma unroll
            for (int c = 0; c < 8; ++c) acc[r][c] = 0.f;

        for (int k = 0; k < H_; k += 4) {
            float4 av[4];
            #pragma unroll
            for (int r = 0; r < 4; ++r)
                av[r] = *reinterpret_cast<const float4*>(&sH1[(r0 + r) * H_ + k]);
            #pragma unroll
            for (int kk = 0; kk < 4; ++kk) {
                float4 wA = *reinterpret_cast<const float4*>(&W2[(k + kk) * H_ + c0]);
                float4 wB = *reinterpret_cast<const float4*>(&W2[(k + kk) * H_ + c0 + 4]);
                #pragma unroll
                for (int r = 0; r < 4; ++r) {
                    float a_ = reinterpret_cast<const float*>(&av[r])[kk];
                    acc[r][0] = fmaf(a_, wA.x, acc[r][0]);
                    acc[r][1] = fmaf(a_, wA.y, acc[r][1]);
                    acc[r][2] = fmaf(a_, wA.z, acc[r][2]);
                    acc[r][3] = fmaf(a_, wA.w, acc[r][3]);
                    acc[r][4] = fmaf(a_, wB.x, acc[r][4]);
                    acc[r][5] = fmaf(a_, wB.y, acc[r][5]);
                    acc[r][6] = fmaf(a_, wB.z, acc[r][6]);
                    acc[r][7] = fmaf(a_, wB.w, acc[r][7]);
                }
            }
        }
        #pragma unroll
        for (int r = 0; r < 4; ++r)
            #pragma unroll
            for (int c = 0; c < 8; ++c)
                sH2[(r0 + r) * H_ + c0 + c] = ssp_f(acc[r][c] * INV_SQRT_H);
    }
    __syncthreads();

    // ---------------- Phase 3: layer 3  Rw[64][112] = H2 @ W3 / sqrt(H) --------
    // 224 active threads = 8 rowTiles(8 rows) x 28 colTiles(4 cols)
    {
        const int rt = tid / 28, ct = tid % 28;
        if (rt < 8) {
            const int r0 = rt * 8, c0 = ct * 4;
            float acc[8][4];
            #pragma unroll
            for (int r = 0; r < 8; ++r)
                #pragma unroll
                for (int c = 0; c < 4; ++c) acc[r][c] = 0.f;

            for (int k = 0; k < H_; k += 4) {
                float4 av[8];
                #pragma unroll
                for (int r = 0; r < 8; ++r)
                    av[r] = *reinterpret_cast<const float4*>(&sH2[(r0 + r) * H_ + k]);
                #pragma unroll
                for (int kk = 0; kk < 4; ++kk) {
                    float4 w = *reinterpret_cast<const float4*>(&W3[(k + kk) * MOUT_ + c0]);
                    #pragma unroll
                    for (int r = 0; r < 8; ++r) {
                        float a_ = reinterpret_cast<const float*>(&av[r])[kk];
                        acc[r][0] = fmaf(a_, w.x, acc[r][0]);
                        acc[r][1] = fmaf(a_, w.y, acc[r][1]);
                        acc[r][2] = fmaf(a_, w.z, acc[r][2]);
                        acc[r][3] = fmaf(a_, w.w, acc[r][3]);
                    }
                }
            }
            // NOTE: sRw aliases sH1 (dead after phase 2 reads completed at last barrier)
            #pragma unroll
            for (int r = 0; r < 8; ++r)
                #pragma unroll
                for (int c = 0; c < 4; ++c)
                    sRw[(r0 + r) * MOUT_ + c0 + c] = acc[r][c] * INV_SQRT_H;
        }
    }
    __syncthreads();

    // ---------------- Phase 4: contraction with feats & Y ----------------------
    // out[z,a] = sum_b sum_j K[z,a,b,j] * feats[z,b,j]
    // 4 threads per b (q = quarter of the u-ranges)
    {
        const int b = tid >> 2, q = tid & 3;
        const float* f = rep + (size_t)(z * 64 + b) * 240;
        const float* Rb = &sRw[b * MOUT_];
        float dot = 0.f;

        // l=0: u in [q*16, q*16+16)
        {
            float s = 0.f;
            #pragma unroll
            for (int j = 0; j < 4; ++j) {
                float4 v = *reinterpret_cast<const float4*>(&f[q * 16 + j * 4]);
                const float* vp = reinterpret_cast<const float*>(&v);
                #pragma unroll
                for (int c = 0; c < 4; ++c)
                    s = fmaf(vp[c], Rb[q * 16 + j * 4 + c], s);
            }
            dot = fmaf(s, NORM0, dot);
        }
        // l=1: u in [q*8, q*8+8), features at f[64 + 3u + c]
        {
            float v[24];
            #pragma unroll
            for (int j = 0; j < 6; ++j)
                *reinterpret_cast<float4*>(&v[j * 4]) =
                    *reinterpret_cast<const float4*>(&f[64 + q * 24 + j * 4]);
            float y0 = sY1[b][0], y1 = sY1[b][1], y2 = sY1[b][2];
            float s = 0.f;
            #pragma unroll
            for (int uu = 0; uu < 8; ++uu) {
                float g = y0 * v[uu * 3] + y1 * v[uu * 3 + 1] + y2 * v[uu * 3 + 2];
                s = fmaf(Rb[64 + q * 8 + uu], g, s);
            }
            dot = fmaf(s, NORM1, dot);
        }
        // l=2: u in [q*4, q*4+4), features at f[160 + 5u + c]
        {
            float v[20];
            #pragma unroll
            for (int j = 0; j < 5; ++j)
                *reinterpret_cast<float4*>(&v[j * 4]) =
                    *reinterpret_cast<const float4*>(&f[160 + q * 20 + j * 4]);
            float s = 0.f;
            #pragma unroll
            for (int uu = 0; uu < 4; ++uu) {
                float g = 0.f;
                #pragma unroll
                for (int c = 0; c < 5; ++c)
                    g = fmaf(sY2[b][c], v[uu * 5 + c], g);
                s = fmaf(Rb[96 + q * 4 + uu], g, s);
            }
            dot = fmaf(s, NORM2, dot);
        }
        sPart[tid] = dot;
    }
    __syncthreads();

    if (tid < 64) {
        float s = sPart[tid * 4] + sPart[tid * 4 + 1] + sPart[tid * 4 + 2] + sPart[tid * 4 + 3];
        #pragma unroll
        for (int off = 32; off > 0; off >>= 1)
            s += __shfl_xor(s, off);
        if (tid == 0) {
            float total = s * sInv;               // feats 1/sqrt(n_atoms) folded here
            out[z * 64 + a] = sp_f(total) * sMask[a];
        }
    }
}

extern "C" void kernel_launch(void* const* d_in, const int* in_sizes, int n_in,
                              void* d_out, int out_size, void* d_ws, size_t ws_size,
                              hipStream_t stream) {
    const float* rep  = (const float*)d_in[0];
    const float* geom = (const float*)d_in[1];
    const float* mask = (const float*)d_in[2];
    const float* W1   = (const float*)d_in[3];
    const float* W2   = (const float*)d_in[4];
    const float* W3   = (const float*)d_in[5];
    float* out = (float*)d_out;

    dim3 grid(64, 64);   // (a, z)
    outnet_kernel<<<grid, 256, 0, stream>>>(rep, geom, mask, W1, W2, W3, out);
}

// Round 2
// 254.451 us; speedup vs baseline: 1.8623x; 1.8623x over previous
//
#include <hip/hip_runtime.h>
#include <math.h>

// B=64, A=64, MULS=((64,0),(32,1),(16,2)) -> DIM_IN=240, NB=32, H=128, MOUT=112
#define H_ 128
#define NB_ 32
#define NPAIR 2080          // 64*65/2 unordered pairs (incl. diagonal)
#define PAIR_TILE 64
#define NTILE 33            // ceil(2080/64)

#define INV_STEP 3.1f
#define HALF_PI 1.57079632679489662f
#define INV_SQRT_NB 0.17677669529663689f
#define INV_SQRT_H 0.08838834764831845f
#define NORM0 0.125f
#define NORM1 0.10206207261596575f
#define NORM2 0.11180339887498948f
#define S3 1.7320508075688772f
#define S5 2.23606797749979f
#define S15 3.872983346207417f
#define LN2 0.6931471805599453f

__device__ __forceinline__ float ssp_f(float x) {
    float t = 5.0f * x;
    float s = fmaxf(t, 0.0f) + __logf(1.0f + __expf(-fabsf(t)));
    return (s - LN2) * 0.2f;
}
__device__ __forceinline__ float sp_f(float x) {
    float t = 5.0f * x;
    float s = fmaxf(t, 0.0f) + __logf(1.0f + __expf(-fabsf(t)));
    return s * 0.2f;
}

// ws layout: acc[4096] floats @ 0; vecs @ 16384 bytes: [z][b][9][128] fp32 (18.9 MB)
#define VECS_OFF 16384

// ---------------------------------------------------------------------------
// Kernel A: per (z,b) precompute v0 = norm0*W3_0@F0, v1[m]=norm1*W3_1@F1[:,m],
// v2[m]=norm2*W3_2@F2[:,m]  (9 vectors of 128). Also zero the accumulator.
// Grid (64, 16), 256 threads; 4 b per block, each thread 2 b x 1 h.
// ---------------------------------------------------------------------------
__global__ __launch_bounds__(256, 2)
void precompute_v(const float* __restrict__ rep, const float* __restrict__ W3,
                  float* __restrict__ ws) {
    const int z = blockIdx.x, bq = blockIdx.y;
    const int tid = threadIdx.x;

    // zero accumulator (runs before kernel B, stream-ordered)
    if (bq == 0 && tid < 64) ws[z * 64 + tid] = 0.0f;

    __shared__ float sW3[128 * 113];  // stride 113 breaks (112%32==16) bank alias
    __shared__ float sRep[4 * 240];

    for (int idx = tid; idx < 128 * 112; idx += 256) {
        int h = idx / 112, c = idx - h * 112;
        sW3[h * 113 + c] = W3[idx];
    }
    for (int idx = tid; idx < 4 * 240; idx += 256)
        sRep[idx] = rep[((size_t)(z * 64 + bq * 4)) * 240 + idx];
    __syncthreads();

    const int h = tid & 127;
    const int half = tid >> 7;
    float* vecs = ws + VECS_OFF / 4;
    const float* wrow = &sW3[h * 113];

    #pragma unroll
    for (int j = 0; j < 2; ++j) {
        const int bl = half * 2 + j;
        const float* rrow = &sRep[bl * 240];
        float* vb = vecs + ((size_t)(z * 64 + bq * 4 + bl) * 9) * 128;

        float s0 = 0.f;
        #pragma unroll 8
        for (int c = 0; c < 64; ++c) s0 = fmaf(wrow[c], rrow[c], s0);
        vb[0 * 128 + h] = s0 * NORM0;

        #pragma unroll
        for (int m = 0; m < 3; ++m) {
            float s = 0.f;
            #pragma unroll 8
            for (int uu = 0; uu < 32; ++uu)
                s = fmaf(wrow[64 + uu], rrow[64 + 3 * uu + m], s);
            vb[(1 + m) * 128 + h] = s * NORM1;
        }
        #pragma unroll
        for (int m = 0; m < 5; ++m) {
            float s = 0.f;
            #pragma unroll 8
            for (int uu = 0; uu < 16; ++uu)
                s = fmaf(wrow[96 + uu], rrow[160 + 5 * uu + m], s);
            vb[(4 + m) * 128 + h] = s * NORM2;
        }
    }
}

// ---------------------------------------------------------------------------
// Kernel B: per z, tile of 64 unordered pairs. Layer1 (sparse basis) -> sH1,
// layer2 GEMM 64x128 @ 128x128 (W2 chunked through LDS, 8x4 thread tiles,
// H2 stays in registers), ssp, then register combine with precomputed v's and
// atomicAdd both directions into the accumulator.
// ---------------------------------------------------------------------------
__global__ __launch_bounds__(256, 3)
void pair_mlp(const float* __restrict__ geom, const float* __restrict__ W1,
              const float* __restrict__ W2, float* __restrict__ ws) {
    const int z = blockIdx.y;
    const int tid = threadIdx.x;

    __shared__ __align__(16) float sH1[PAIR_TILE * H_];   // 32 KB
    __shared__ __align__(16) float sW2[32 * H_];          // 16 KB chunk
    __shared__ float sGeom[64 * 3];
    __shared__ int   sPA[PAIR_TILE], sPB[PAIR_TILE];
    __shared__ float sY1[PAIR_TILE][3], sY2[PAIR_TILE][5];
    __shared__ int   sI0[PAIR_TILE], sI1[PAIR_TILE];
    __shared__ float sC0[PAIR_TILE], sC1[PAIR_TILE];

    // ---- decode pairs + geometry ----
    if (tid < 192) sGeom[tid] = geom[z * 192 + tid];
    if (tid < PAIR_TILE) {
        int p = blockIdx.x * PAIR_TILE + tid;
        int a = -1, b = 0;
        if (p < NPAIR) {
            int rem = p, aa = 0;
            while (rem >= 64 - aa) { rem -= 64 - aa; ++aa; }
            a = aa; b = aa + rem;
        }
        sPA[tid] = a; sPB[tid] = b;
    }
    __syncthreads();
    if (tid < PAIR_TILE) {
        int a = sPA[tid], b = sPB[tid];
        float dx = 0.f, dy = 0.f, dz = 0.f;
        if (a >= 0) {
            dx = sGeom[a * 3 + 0] - sGeom[b * 3 + 0];
            dy = sGeom[a * 3 + 1] - sGeom[b * 3 + 1];
            dz = sGeom[a * 3 + 2] - sGeom[b * 3 + 2];
        }
        float r2 = dx * dx + dy * dy + dz * dz;
        float r = sqrtf(fmaxf(r2, 1e-12f));
        float nz = (r2 > 1e-10f) ? 1.0f : 0.0f;
        float ir = 1.0f / r;
        float x = dx * ir, y = dy * ir, zz = dz * ir;
        sY1[tid][0] = S3 * x * nz;
        sY1[tid][1] = S3 * y * nz;
        sY1[tid][2] = S3 * zz * nz;
        sY2[tid][0] = S15 * x * y * nz;
        sY2[tid][1] = S15 * y * zz * nz;
        sY2[tid][2] = 0.5f * S5 * (3.0f * zz * zz - 1.0f) * nz;
        sY2[tid][3] = S15 * x * zz * nz;
        sY2[tid][4] = 0.5f * S15 * (x * x - y * y) * nz;
        // cosine basis: at most 2 nonzero centers
        float u = r * INV_STEP;
        int i0 = (int)floorf(u);
        float d0 = u - (float)i0;
        float c0 = (i0 >= 0 && i0 < NB_) ? __cosf(HALF_PI * d0) : 0.f;
        int i1 = i0 + 1;
        float d1 = d0 - 1.0f;
        float c1 = (i1 >= 0 && i1 < NB_ && d1 > -1.0f) ? __cosf(HALF_PI * d1) : 0.f;
        sI0[tid] = min(max(i0, 0), NB_ - 1); sC0[tid] = c0 * INV_SQRT_NB;
        sI1[tid] = min(max(i1, 0), NB_ - 1); sC1[tid] = c1 * INV_SQRT_NB;
    }
    __syncthreads();

    // ---- layer 1: sH1[64][128] ----
    {
        const int col = tid & 127;
        const int pg = (tid >> 7) * 32;
        for (int i = 0; i < 32; ++i) {
            const int pr = pg + i;
            float acc = sC0[pr] * W1[sI0[pr] * H_ + col]
                      + sC1[pr] * W1[sI1[pr] * H_ + col];
            sH1[pr * H_ + col] = ssp_f(acc);
        }
    }
    __syncthreads();

    // ---- layer 2 GEMM: 64x128 = sH1 @ W2, thread tile 8 rows x 4 cols ----
    const int rt = tid >> 5, ct = tid & 31;
    const int r0 = rt * 8, c0 = ct * 4;
    float acc[8][4];
    #pragma unroll
    for (int r = 0; r < 8; ++r)
        #pragma unroll
        for (int c = 0; c < 4; ++c) acc[r][c] = 0.f;

    for (int kc = 0; kc < 4; ++kc) {
        for (int idx = tid; idx < 32 * H_; idx += 256)
            sW2[idx] = W2[kc * 32 * H_ + idx];
        __syncthreads();
        #pragma unroll
        for (int k4 = 0; k4 < 8; ++k4) {
            const int kb = kc * 32 + k4 * 4;
            float4 av[8];
            #pragma unroll
            for (int r = 0; r < 8; ++r)
                av[r] = *reinterpret_cast<const float4*>(&sH1[(r0 + r) * H_ + kb]);
            #pragma unroll
            for (int kk = 0; kk < 4; ++kk) {
                float4 w = *reinterpret_cast<const float4*>(&sW2[(k4 * 4 + kk) * H_ + c0]);
                #pragma unroll
                for (int r = 0; r < 8; ++r) {
                    float a_ = reinterpret_cast<const float*>(&av[r])[kk];
                    acc[r][0] = fmaf(a_, w.x, acc[r][0]);
                    acc[r][1] = fmaf(a_, w.y, acc[r][1]);
                    acc[r][2] = fmaf(a_, w.z, acc[r][2]);
                    acc[r][3] = fmaf(a_, w.w, acc[r][3]);
                }
            }
        }
        __syncthreads();
    }

    // ---- ssp in registers: H2 tile ----
    #pragma unroll
    for (int r = 0; r < 8; ++r)
        #pragma unroll
        for (int c = 0; c < 4; ++c)
            acc[r][c] = ssp_f(acc[r][c] * INV_SQRT_H);

    // ---- combine: u_ab = v0[b] + Y1.v1[b] + Y2.v2[b]; u_ba flips Y1 sign ----
    float* accBuf = ws;
    const float* vecs = ws + VECS_OFF / 4;

    for (int r = 0; r < 8; ++r) {
        const int row = r0 + r;
        const int a = sPA[row], b = sPB[row];
        float ca = 0.f, cb = 0.f;
        if (a >= 0) {
            const float y10 = sY1[row][0], y11 = sY1[row][1], y12 = sY1[row][2];
            const float y20 = sY2[row][0], y21 = sY2[row][1], y22 = sY2[row][2],
                        y23 = sY2[row][3], y24 = sY2[row][4];
            const float* vb = vecs + ((size_t)(z * 64 + b) * 9) * 128 + c0;
            const float* va = vecs + ((size_t)(z * 64 + a) * 9) * 128 + c0;
            #pragma unroll
            for (int c = 0; c < 4; ++c) {
                float v0b = vb[c],           v0a = va[c];
                float e1b = vb[128 + c],     e1a = va[128 + c];
                float e2b = vb[256 + c],     e2a = va[256 + c];
                float e3b = vb[384 + c],     e3a = va[384 + c];
                float f0b = vb[512 + c],     f0a = va[512 + c];
                float f1b = vb[640 + c],     f1a = va[640 + c];
                float f2b = vb[768 + c],     f2a = va[768 + c];
                float f3b = vb[896 + c],     f3a = va[896 + c];
                float f4b = vb[1024 + c],    f4a = va[1024 + c];
                float ub = v0b + y10 * e1b + y11 * e2b + y12 * e3b
                         + y20 * f0b + y21 * f1b + y22 * f2b + y23 * f3b + y24 * f4b;
                float ua = v0a - y10 * e1a - y11 * e2a - y12 * e3a
                         + y20 * f0a + y21 * f1a + y22 * f2a + y23 * f3a + y24 * f4a;
                ca = fmaf(acc[r][c], ub, ca);
                cb = fmaf(acc[r][c], ua, cb);
            }
        }
        // reduce over the 32 colTile lanes (same rt -> contiguous 32-lane group)
        #pragma unroll
        for (int off = 16; off > 0; off >>= 1) {
            ca += __shfl_xor(ca, off);
            cb += __shfl_xor(cb, off);
        }
        if (ct == 0 && a >= 0) {
            atomicAdd(&accBuf[z * 64 + a], ca * INV_SQRT_H);
            if (b != a) atomicAdd(&accBuf[z * 64 + b], cb * INV_SQRT_H);
        }
    }
}

// ---------------------------------------------------------------------------
// Kernel C: out[z,a] = softplus-like(acc * 1/sqrt(n_atoms)) * mask
// ---------------------------------------------------------------------------
__global__ __launch_bounds__(64, 8)
void finalize(const float* __restrict__ ws, const float* __restrict__ mask,
              float* __restrict__ out) {
    const int z = blockIdx.x, a = threadIdx.x;
    const float m = mask[z * 64 + a];
    float s = m;
    #pragma unroll
    for (int off = 32; off > 0; off >>= 1) s += __shfl_xor(s, off);
    const float inv = rsqrtf(s);
    out[z * 64 + a] = sp_f(ws[z * 64 + a] * inv) * m;
}

extern "C" void kernel_launch(void* const* d_in, const int* in_sizes, int n_in,
                              void* d_out, int out_size, void* d_ws, size_t ws_size,
                              hipStream_t stream) {
    const float* rep  = (const float*)d_in[0];
    const float* geom = (const float*)d_in[1];
    const float* mask = (const float*)d_in[2];
    const float* W1   = (const float*)d_in[3];
    const float* W2   = (const float*)d_in[4];
    const float* W3   = (const float*)d_in[5];
    float* out = (float*)d_out;
    float* ws  = (float*)d_ws;

    precompute_v<<<dim3(64, 16), 256, 0, stream>>>(rep, W3, ws);
    pair_mlp<<<dim3(NTILE, 64), 256, 0, stream>>>(geom, W1, W2, ws);
    finalize<<<64, 64, 0, stream>>>(ws, mask, out);
}

// Round 3
// 202.785 us; speedup vs baseline: 2.3367x; 1.2548x over previous
//
#include <hip/hip_runtime.h>
#include <math.h>

// B=64, A=64, MULS=((64,0),(32,1),(16,2)) -> DIM_IN=240, NB=32, H=128, MOUT=112
#define H_ 128
#define NB_ 32
#define NPAIR 2080          // 64*65/2 unordered pairs (incl. diagonal)
#define PAIR_TILE 64
#define NTILE 33            // ceil(2080/64)

#define INV_STEP 3.1f
#define HALF_PI 1.57079632679489662f
#define INV_SQRT_NB 0.17677669529663689f
#define INV_SQRT_H 0.08838834764831845f
#define NORM0 0.125f
#define NORM1 0.10206207261596575f
#define NORM2 0.11180339887498948f
#define S3 1.7320508075688772f
#define S5 2.23606797749979f
#define S15 3.872983346207417f
#define LN2 0.6931471805599453f

typedef __attribute__((ext_vector_type(8))) short short8;
typedef __attribute__((ext_vector_type(4))) float f32x4;

// ws layout (big mode): w2hi @0 (32768 B), w2lo @32768 (32768 B), vecs @65536
// ws layout (small mode): vecs @0. Accumulator lives in d_out (zeroed first).
#define VECS_BYTES (64ull * 64 * 9 * 128 * 4)   // 18874368
#define NEED_BIG (65536ull + VECS_BYTES)

__device__ __forceinline__ float ssp_f(float x) {
    float t = 5.0f * x;
    float s = fmaxf(t, 0.0f) + __logf(1.0f + __expf(-fabsf(t)));
    return (s - LN2) * 0.2f;
}
__device__ __forceinline__ float sp_f(float x) {
    float t = 5.0f * x;
    float s = fmaxf(t, 0.0f) + __logf(1.0f + __expf(-fabsf(t)));
    return s * 0.2f;
}
__device__ __forceinline__ unsigned short f2bf(float x) {
    unsigned u = __float_as_uint(x);
    return (unsigned short)((u + 0x7FFFu + ((u >> 16) & 1u)) >> 16);
}
__device__ __forceinline__ float bf2f(unsigned short s) {
    return __uint_as_float(((unsigned)s) << 16);
}

// ---------------------------------------------------------------------------
// zero the accumulator (d_out is poisoned 0xAA before every timed call)
// ---------------------------------------------------------------------------
__global__ void zero_out(float* __restrict__ out) {
    out[blockIdx.x * 256 + threadIdx.x] = 0.0f;
}

// ---------------------------------------------------------------------------
// big mode: split W2 into MFMA-B-fragment-ordered bf16 hi/lo arrays.
// frag element pos = ((kt*8+nt)*64 + lane)*8 + j ; value = W2[k][n],
// k = kt*32 + (lane>>4)*8 + j, n = nt*16 + (lane&15)
// ---------------------------------------------------------------------------
__global__ void w2split(const float* __restrict__ W2,
                        unsigned short* __restrict__ w2h,
                        unsigned short* __restrict__ w2l) {
    int e0 = (blockIdx.x * 256 + threadIdx.x) * 4;
    #pragma unroll
    for (int t = 0; t < 4; ++t) {
        int pos = e0 + t;
        int j = pos & 7, lane = (pos >> 3) & 63, fn = pos >> 9;
        int kt = fn >> 3, nt = fn & 7;
        int k = kt * 32 + (lane >> 4) * 8 + j;
        int n = nt * 16 + (lane & 15);
        float w = W2[k * 128 + n];
        unsigned short h = f2bf(w);
        w2h[pos] = h;
        w2l[pos] = f2bf(w - bf2f(h));
    }
}

// ---------------------------------------------------------------------------
// precompute_v: per (z, b-half, h-half): V[b][cm][h] = sum_u F~[b,seg]·W3T·norm
// Register-tiled fp32 GEMM: thread tile 4b x 2h per cm-component.
// F~ = per-b permuted rep (segment-major); W3T staged with norms folded.
// ---------------------------------------------------------------------------
__global__ __launch_bounds__(256, 2)
void precompute_v(const float* __restrict__ rep, const float* __restrict__ W3,
                  float* __restrict__ vecs) {
    const int z = blockIdx.x;
    const int bh = blockIdx.y >> 1, hh = blockIdx.y & 1;
    const int tid = threadIdx.x;

    __shared__ __align__(16) float sF[32 * 240];    // 30720 B
    __shared__ __align__(16) float sBT[112 * 64];   // 28672 B

    const float* repz = rep + ((size_t)z * 64 + bh * 32) * 240;
    for (int idx = tid; idx < 1920; idx += 256) {
        int b = idx / 60, q = idx - b * 60, j0 = q * 4;
        float4 v = *reinterpret_cast<const float4*>(repz + b * 240 + j0);
        const float* vp = reinterpret_cast<const float*>(&v);
        #pragma unroll
        for (int c = 0; c < 4; ++c) {
            int j = j0 + c, p;
            if (j < 64) p = j;
            else if (j < 160) { int t = j - 64; int u = t / 3; int m = t - u * 3; p = 64 + m * 32 + u; }
            else { int t = j - 160; int u = t / 5; int m = t - u * 5; p = 160 + m * 16 + u; }
            sF[b * 240 + p] = vp[c];
        }
    }
    for (int idx = tid; idx < 1792; idx += 256) {
        int hp = idx / 28, q = idx - hp * 28, m0 = q * 4;
        float4 v = *reinterpret_cast<const float4*>(W3 + (size_t)(hh * 64 + hp) * 112 + m0);
        const float* vp = reinterpret_cast<const float*>(&v);
        #pragma unroll
        for (int c = 0; c < 4; ++c) {
            int m = m0 + c;
            float nrm = (m < 64) ? NORM0 : ((m < 96) ? NORM1 : NORM2);
            sBT[m * 64 + hp] = vp[c] * nrm;
        }
    }
    __syncthreads();

    const int b0 = (tid >> 5) * 4;
    const int h0 = (tid & 31) * 2;

    #pragma unroll
    for (int cm = 0; cm < 9; ++cm) {
        const int Aoff[9] = {0, 64, 96, 128, 160, 176, 192, 208, 224};
        const int Boff[9] = {0, 64, 64, 64, 96, 96, 96, 96, 96};
        const int Klen[9] = {64, 32, 32, 32, 16, 16, 16, 16, 16};
        const int ao = Aoff[cm], bo = Boff[cm], K = Klen[cm];
        float acc0[4] = {0.f, 0.f, 0.f, 0.f};
        float acc1[4] = {0.f, 0.f, 0.f, 0.f};
        for (int u = 0; u < K; u += 4) {
            float4 av[4];
            #pragma unroll
            for (int r = 0; r < 4; ++r)
                av[r] = *reinterpret_cast<const float4*>(sF + (b0 + r) * 240 + ao + u);
            #pragma unroll
            for (int uu = 0; uu < 4; ++uu) {
                float2 bv = *reinterpret_cast<const float2*>(sBT + (bo + u + uu) * 64 + h0);
                #pragma unroll
                for (int r = 0; r < 4; ++r) {
                    float a_ = reinterpret_cast<const float*>(&av[r])[uu];
                    acc0[r] = fmaf(a_, bv.x, acc0[r]);
                    acc1[r] = fmaf(a_, bv.y, acc1[r]);
                }
            }
        }
        #pragma unroll
        for (int r = 0; r < 4; ++r) {
            float2 st; st.x = acc0[r]; st.y = acc1[r];
            *reinterpret_cast<float2*>(vecs +
                (((size_t)z * 64 + bh * 32 + b0 + r) * 9 + cm) * 128 + hh * 64 + h0) = st;
        }
    }
}

// ---------------------------------------------------------------------------
// pair_mlp: 64 unordered pairs/block. Layer1 -> A-frags (bf16 hi/lo) in LDS;
// layer2 = 3-way split bf16 MFMA (16x16x32); H2 -> LDS; combine with
// precomputed v's; atomicAdd both directions into accumulator (d_out).
// ---------------------------------------------------------------------------
template <bool FRAGS>
__global__ __launch_bounds__(256, 4)
void pair_mlp(const float* __restrict__ geom, const float* __restrict__ W1,
              const float* __restrict__ W2,
              const unsigned short* __restrict__ w2h,
              const unsigned short* __restrict__ w2l,
              const float* __restrict__ vecs, float* __restrict__ accOut) {
    const int z = blockIdx.y;
    const int tid = threadIdx.x;

    // union: A-frags (hi 16K + lo 16K) then H2 f32 [64][132] (33792 B)
    __shared__ __align__(16) char sBigRaw[64 * 132 * 4];
    short* sAhi = reinterpret_cast<short*>(sBigRaw);
    short* sAlo = reinterpret_cast<short*>(sBigRaw + 16384);
    float* sH2  = reinterpret_cast<float*>(sBigRaw);

    __shared__ float sGeom[64 * 3];
    __shared__ int   sPA[PAIR_TILE], sPB[PAIR_TILE];
    __shared__ float sY1[PAIR_TILE][3], sY2[PAIR_TILE][5];
    __shared__ int   sI0[PAIR_TILE], sI1[PAIR_TILE];
    __shared__ float sC0[PAIR_TILE], sC1[PAIR_TILE];

    if (tid < 192) sGeom[tid] = geom[z * 192 + tid];
    if (tid < PAIR_TILE) {
        int p = blockIdx.x * PAIR_TILE + tid;
        int a = -1, b = 0;
        if (p < NPAIR) {
            int rem = p, aa = 0;
            while (rem >= 64 - aa) { rem -= 64 - aa; ++aa; }
            a = aa; b = aa + rem;
        }
        sPA[tid] = a; sPB[tid] = b;
    }
    __syncthreads();
    if (tid < PAIR_TILE) {
        int a = sPA[tid], b = sPB[tid];
        float dx = 0.f, dy = 0.f, dz = 0.f;
        if (a >= 0) {
            dx = sGeom[a * 3 + 0] - sGeom[b * 3 + 0];
            dy = sGeom[a * 3 + 1] - sGeom[b * 3 + 1];
            dz = sGeom[a * 3 + 2] - sGeom[b * 3 + 2];
        }
        float r2 = dx * dx + dy * dy + dz * dz;
        float r = sqrtf(fmaxf(r2, 1e-12f));
        float nz = (r2 > 1e-10f) ? 1.0f : 0.0f;
        float ir = 1.0f / r;
        float x = dx * ir, y = dy * ir, zz = dz * ir;
        sY1[tid][0] = S3 * x * nz;
        sY1[tid][1] = S3 * y * nz;
        sY1[tid][2] = S3 * zz * nz;
        sY2[tid][0] = S15 * x * y * nz;
        sY2[tid][1] = S15 * y * zz * nz;
        sY2[tid][2] = 0.5f * S5 * (3.0f * zz * zz - 1.0f) * nz;
        sY2[tid][3] = S15 * x * zz * nz;
        sY2[tid][4] = 0.5f * S15 * (x * x - y * y) * nz;
        float u = r * INV_STEP;
        int i0 = (int)floorf(u);
        float d0 = u - (float)i0;
        float c0 = (i0 >= 0 && i0 < NB_) ? __cosf(HALF_PI * d0) : 0.f;
        int i1 = i0 + 1;
        float d1 = d0 - 1.0f;
        float c1 = (i1 >= 0 && i1 < NB_ && d1 > -1.0f) ? __cosf(HALF_PI * d1) : 0.f;
        sI0[tid] = min(max(i0, 0), NB_ - 1); sC0[tid] = c0 * INV_SQRT_NB;
        sI1[tid] = min(max(i1, 0), NB_ - 1); sC1[tid] = c1 * INV_SQRT_NB;
    }
    __syncthreads();

    // ---- layer 1 -> A-fragments (thread = (pr, k-octet seg)) ----
    {
        const int pr = tid & 63, seg = tid >> 6;
        const float* w1r0 = W1 + sI0[pr] * H_;
        const float* w1r1 = W1 + sI1[pr] * H_;
        const float c0 = sC0[pr], c1 = sC1[pr];
        const int lane = seg * 16 + (pr & 15);
        const int g = pr >> 4;
        #pragma unroll
        for (int kt = 0; kt < 4; ++kt) {
            const int k0 = kt * 32 + seg * 8;
            float4 a0 = *reinterpret_cast<const float4*>(w1r0 + k0);
            float4 a1 = *reinterpret_cast<const float4*>(w1r0 + k0 + 4);
            float4 b0 = *reinterpret_cast<const float4*>(w1r1 + k0);
            float4 b1 = *reinterpret_cast<const float4*>(w1r1 + k0 + 4);
            const float* ap = reinterpret_cast<const float*>(&a0);
            const float* bp = reinterpret_cast<const float*>(&b0);
            short8 hi8, lo8;
            #pragma unroll
            for (int j = 0; j < 8; ++j) {
                float w0 = (j < 4) ? ap[j] : reinterpret_cast<const float*>(&a1)[j - 4];
                float w1v = (j < 4) ? bp[j] : reinterpret_cast<const float*>(&b1)[j - 4];
                float xv = ssp_f(c0 * w0 + c1 * w1v);
                unsigned short h = f2bf(xv);
                hi8[j] = (short)h;
                lo8[j] = (short)f2bf(xv - bf2f(h));
            }
            const int off = ((g * 4 + kt) * 64 + lane) * 8;
            *reinterpret_cast<short8*>(sAhi + off) = hi8;
            *reinterpret_cast<short8*>(sAlo + off) = lo8;
        }
    }
    __syncthreads();

    // ---- layer 2: 3-way split bf16 MFMA. wave wv owns pair rows 16wv.. ----
    const int wv = tid >> 6;
    const int lane = tid & 63;
    f32x4 acc[8];
    #pragma unroll
    for (int nt = 0; nt < 8; ++nt) { acc[nt][0] = 0.f; acc[nt][1] = 0.f; acc[nt][2] = 0.f; acc[nt][3] = 0.f; }

    #pragma unroll
    for (int kt = 0; kt < 4; ++kt) {
        const int aoff = ((wv * 4 + kt) * 64 + lane) * 8;
        short8 ah = *reinterpret_cast<const short8*>(sAhi + aoff);
        short8 al = *reinterpret_cast<const short8*>(sAlo + aoff);
        #pragma unroll
        for (int nt = 0; nt < 8; ++nt) {
            short8 bh, bl;
            if (FRAGS) {
                const int foff = ((kt * 8 + nt) * 64 + lane) * 8;
                bh = *reinterpret_cast<const short8*>(w2h + foff);
                bl = *reinterpret_cast<const short8*>(w2l + foff);
            } else {
                const int n = nt * 16 + (lane & 15);
                const int kb = kt * 32 + (lane >> 4) * 8;
                #pragma unroll
                for (int j = 0; j < 8; ++j) {
                    float w = W2[(kb + j) * 128 + n];
                    unsigned short h = f2bf(w);
                    bh[j] = (short)h;
                    bl[j] = (short)f2bf(w - bf2f(h));
                }
            }
            acc[nt] = __builtin_amdgcn_mfma_f32_16x16x32_bf16(ah, bh, acc[nt], 0, 0, 0);
            acc[nt] = __builtin_amdgcn_mfma_f32_16x16x32_bf16(ah, bl, acc[nt], 0, 0, 0);
            acc[nt] = __builtin_amdgcn_mfma_f32_16x16x32_bf16(al, bh, acc[nt], 0, 0, 0);
        }
    }
    __syncthreads();   // A-frag region dead; safe to overwrite with sH2

    // ---- ssp + write H2 to LDS (stride 132: 2-way bank alias only) ----
    {
        const int quad = lane >> 4, n15 = lane & 15;
        #pragma unroll
        for (int nt = 0; nt < 8; ++nt) {
            #pragma unroll
            for (int reg = 0; reg < 4; ++reg) {
                const int row = wv * 16 + quad * 4 + reg;
                sH2[row * 132 + nt * 16 + n15] = ssp_f(acc[nt][reg] * INV_SQRT_H);
            }
        }
    }
    __syncthreads();

    // ---- combine with precomputed v's; atomicAdd both directions ----
    {
        const int rt = tid >> 5, ct = tid & 31;
        const int r0 = rt * 8, c0 = ct * 4;
        for (int r = 0; r < 8; ++r) {
            const int row = r0 + r;
            const int a = sPA[row], b = sPB[row];
            float ca = 0.f, cb = 0.f;
            if (a >= 0) {
                float4 hv = *reinterpret_cast<const float4*>(sH2 + row * 132 + c0);
                const float* hp = reinterpret_cast<const float*>(&hv);
                const float y10 = sY1[row][0], y11 = sY1[row][1], y12 = sY1[row][2];
                const float y20 = sY2[row][0], y21 = sY2[row][1], y22 = sY2[row][2],
                            y23 = sY2[row][3], y24 = sY2[row][4];
                const float* vb = vecs + ((size_t)(z * 64 + b) * 9) * 128 + c0;
                const float* va = vecs + ((size_t)(z * 64 + a) * 9) * 128 + c0;
                #pragma unroll
                for (int c = 0; c < 4; ++c) {
                    float ub = vb[c] + y10 * vb[128 + c] + y11 * vb[256 + c] + y12 * vb[384 + c]
                             + y20 * vb[512 + c] + y21 * vb[640 + c] + y22 * vb[768 + c]
                             + y23 * vb[896 + c] + y24 * vb[1024 + c];
                    float ua = va[c] - y10 * va[128 + c] - y11 * va[256 + c] - y12 * va[384 + c]
                             + y20 * va[512 + c] + y21 * va[640 + c] + y22 * va[768 + c]
                             + y23 * va[896 + c] + y24 * va[1024 + c];
                    ca = fmaf(hp[c], ub, ca);
                    cb = fmaf(hp[c], ua, cb);
                }
            }
            #pragma unroll
            for (int off = 16; off > 0; off >>= 1) {
                ca += __shfl_xor(ca, off);
                cb += __shfl_xor(cb, off);
            }
            if (ct == 0 && a >= 0) {
                atomicAdd(&accOut[z * 64 + a], ca * INV_SQRT_H);
                if (b != a) atomicAdd(&accOut[z * 64 + b], cb * INV_SQRT_H);
            }
        }
    }
}

// ---------------------------------------------------------------------------
// finalize (in place on d_out): out = sp(acc / sqrt(n_atoms)) * mask
// ---------------------------------------------------------------------------
__global__ __launch_bounds__(64, 8)
void finalize(float* __restrict__ out, const float* __restrict__ mask) {
    const int z = blockIdx.x, a = threadIdx.x;
    const float m = mask[z * 64 + a];
    float s = m;
    #pragma unroll
    for (int off = 32; off > 0; off >>= 1) s += __shfl_xor(s, off);
    const float inv = rsqrtf(s);
    const float v = out[z * 64 + a];
    out[z * 64 + a] = sp_f(v * inv) * m;
}

extern "C" void kernel_launch(void* const* d_in, const int* in_sizes, int n_in,
                              void* d_out, int out_size, void* d_ws, size_t ws_size,
                              hipStream_t stream) {
    const float* rep  = (const float*)d_in[0];
    const float* geom = (const float*)d_in[1];
    const float* mask = (const float*)d_in[2];
    const float* W1   = (const float*)d_in[3];
    const float* W2   = (const float*)d_in[4];
    const float* W3   = (const float*)d_in[5];
    float* out = (float*)d_out;

    const bool big = (ws_size >= NEED_BIG);
    unsigned short* w2h = (unsigned short*)d_ws;
    unsigned short* w2l = (unsigned short*)((char*)d_ws + 32768);
    float* vecs = big ? (float*)((char*)d_ws + 65536) : (float*)d_ws;

    zero_out<<<16, 256, 0, stream>>>(out);
    if (big) w2split<<<16, 256, 0, stream>>>(W2, w2h, w2l);
    precompute_v<<<dim3(64, 4), 256, 0, stream>>>(rep, W3, vecs);
    if (big)
        pair_mlp<true><<<dim3(NTILE, 64), 256, 0, stream>>>(geom, W1, W2, w2h, w2l, vecs, out);
    else
        pair_mlp<false><<<dim3(NTILE, 64), 256, 0, stream>>>(geom, W1, W2, w2h, w2l, vecs, out);
    finalize<<<64, 64, 0, stream>>>(out, mask);
}